// Round 18
// baseline (157.721 us; speedup 1.0000x reference)
//
#include <hip/hip_runtime.h>
#include <hip/hip_bf16.h>

typedef __bf16 bf16_t;
typedef __bf16 bf16x8 __attribute__((ext_vector_type(8)));
typedef __bf16 bf16x4 __attribute__((ext_vector_type(4)));
typedef short short4v __attribute__((ext_vector_type(4)));
typedef float f32x4 __attribute__((ext_vector_type(4)));

constexpr int LD = 3072;

#define MFMA_16x16x32(a, b, c) __builtin_amdgcn_mfma_f32_16x16x32_bf16((a), (b), (c), 0, 0, 0)
#define MFMA16(a, b, c) \
  __builtin_amdgcn_mfma_f32_16x16x16bf16_1k((a), (b), (c), 0, 0, 0)

#define GLOAD_LDS16(g, l)                                               \
  __builtin_amdgcn_global_load_lds(                                     \
      (const __attribute__((address_space(1))) void*)(g),               \
      (__attribute__((address_space(3))) void*)(l), 16, 0, 0)

#define TRREAD(dst, addr, imm) \
  asm volatile("ds_read_b64_tr_b16 %0, %1 offset:" imm : "=v"(dst) : "v"(addr))

#define BAR __builtin_amdgcn_s_barrier()
#define LGKM0 do { asm volatile("s_waitcnt lgkmcnt(0)" ::: "memory"); \
                   __builtin_amdgcn_sched_barrier(0); } while (0)

// ---- fused prep: cvt(x) + tcvt(w_qkv) + tcvt(w_out) in one launch ----
__global__ __launch_bounds__(256) void prep_kernel(
    const float* __restrict__ x, bf16_t* __restrict__ x_b,
    const float* __restrict__ w_qkv, bf16_t* __restrict__ wqT,
    const float* __restrict__ w_out, bf16_t* __restrict__ woT) {
  const int blk = blockIdx.x;
  if (blk < 4096) {
    const int i = blk * 256 + threadIdx.x;
    const float4 a = reinterpret_cast<const float4*>(x)[2 * i];
    const float4 c = reinterpret_cast<const float4*>(x)[2 * i + 1];
    bf16x8 o;
    o[0] = (bf16_t)a.x; o[1] = (bf16_t)a.y; o[2] = (bf16_t)a.z; o[3] = (bf16_t)a.w;
    o[4] = (bf16_t)c.x; o[5] = (bf16_t)c.y; o[6] = (bf16_t)c.z; o[7] = (bf16_t)c.w;
    reinterpret_cast<bf16x8*>(x_b)[i] = o;
    return;
  }
  __shared__ float tile[32][33];
  const float* in; bf16_t* outp; int C, bx, by;
  if (blk < 7168) { const int i = blk - 4096; in = w_qkv; outp = wqT; C = 3072; bx = i % 96; by = i / 96; }
  else            { const int i = blk - 7168; in = w_out; outp = woT; C = 1024; bx = i & 31; by = i >> 5; }
  constexpr int R = 1024;
  const int c0 = bx * 32, r0 = by * 32;
  const int tx = threadIdx.x & 31, ty = threadIdx.x >> 5;
#pragma unroll
  for (int i = 0; i < 32; i += 8)
    tile[ty + i][tx] = in[(size_t)(r0 + ty + i) * C + (c0 + tx)];
  __syncthreads();
#pragma unroll
  for (int i = 0; i < 32; i += 8)
    outp[(size_t)(c0 + ty + i) * R + (r0 + tx)] = (bf16_t)tile[tx][ty + i];
}

// ------------- GEMM1 (QKV): 256x256 tile, 8-phase, counted vmcnt -------------
__global__ __launch_bounds__(512, 2) void gemm_qkv_256(
    const bf16_t* __restrict__ A, const bf16_t* __restrict__ Bt,
    bf16_t* __restrict__ C, float q_scale) {
  constexpr int K = 1024;
  extern __shared__ char smem[];
  char* asB = smem;           // 64 KB: A [2][2][128][64]
  char* bsB = smem + 65536;   // 64 KB: B

  const int t = threadIdx.x;
  const int lane = t & 63, wave = t >> 6;
  const int l15 = lane & 15, lg = lane >> 4;
  const int wr = wave >> 2, wc = wave & 3;

  const int bid = blockIdx.x;
  const int idx = bid >> 3;
  const int rgrp = (bid >> 1) & 3;
  const int cgrp = bid & 1;
  const int brow = (rgrp * 8 + (idx & 7)) * 256;
  const int bcol = (cgrp * 6 + (idx >> 3)) * 256;

  const int srow = t >> 3;
  const int schk = (t & 7) ^ (srow & 7);
  const bf16_t* aS = A + (size_t)(brow + srow) * K + schk * 8;
  const bf16_t* bS = Bt + (size_t)(bcol + srow) * K + schk * 8;
  const int ldst = t * 8;

#define STG_A(T, H) do {                                                      \
    const bf16_t* _s = aS + (size_t)((H) * 128) * K + (T) * 64;               \
    bf16_t* _d = (bf16_t*)(asB + ((T) & 1) * 32768 + (H) * 16384) + ldst;     \
    GLOAD_LDS16(_s, _d);                                                      \
    GLOAD_LDS16(_s + (size_t)64 * K, _d + 4096);                              \
  } while (0)
#define STG_B(T, H) do {                                                      \
    const bf16_t* _s = bS + (size_t)((H) * 128) * K + (T) * 64;               \
    bf16_t* _d = (bf16_t*)(bsB + ((T) & 1) * 32768 + (H) * 16384) + ldst;     \
    GLOAD_LDS16(_s, _d);                                                      \
    GLOAD_LDS16(_s + (size_t)64 * K, _d + 4096);                              \
  } while (0)

  const int rx = l15 & 7;
  const unsigned c0 = ((unsigned)(lg ^ rx)) << 4;
  const unsigned c1 = ((unsigned)((4 | lg) ^ rx)) << 4;
  const unsigned a_rd = (unsigned)(wr * 16384 + l15 * 128);
  const unsigned b_rd = (unsigned)((wc >> 1) * 16384 + (wc & 1) * 8192 + l15 * 128);

  f32x4 acc[8][4] = {};
  bf16x8 af[4][2], bfr[2][2];

#define RD_AF(BUF, MH) do { _Pragma("unroll")                                 \
    for (int m = 0; m < 4; ++m) {                                             \
      const char* _p = asB + (BUF) * 32768 + a_rd + ((MH) * 4 + m) * 2048;    \
      af[m][0] = *(const bf16x8*)(_p + c0);                                   \
      af[m][1] = *(const bf16x8*)(_p + c1); } } while (0)
#define RD_BF(BUF, NH) do { _Pragma("unroll")                                 \
    for (int n = 0; n < 2; ++n) {                                             \
      const char* _p = bsB + (BUF) * 32768 + b_rd + ((NH) * 2 + n) * 2048;    \
      bfr[n][0] = *(const bf16x8*)(_p + c0);                                  \
      bfr[n][1] = *(const bf16x8*)(_p + c1); } } while (0)
#define MM16(MH, NH) do {                                                     \
    __builtin_amdgcn_s_setprio(1);                                            \
    _Pragma("unroll")                                                         \
    for (int m = 0; m < 4; ++m) { _Pragma("unroll")                           \
      for (int n = 0; n < 2; ++n) {                                           \
        acc[(MH)*4+m][(NH)*2+n] =                                             \
            MFMA_16x16x32(af[m][0], bfr[n][0], acc[(MH)*4+m][(NH)*2+n]);      \
        acc[(MH)*4+m][(NH)*2+n] =                                             \
            MFMA_16x16x32(af[m][1], bfr[n][1], acc[(MH)*4+m][(NH)*2+n]); } }  \
    __builtin_amdgcn_s_setprio(0); } while (0)

  STG_A(0, 0); STG_A(0, 1); STG_B(0, 0); STG_B(0, 1); STG_A(1, 0);
  asm volatile("s_waitcnt vmcnt(2)" ::: "memory");
  BAR;

  for (int i = 0; i < 8; ++i) {
    const int T1 = 2 * i + 1, T2 = 2 * i + 2, T3 = 2 * i + 3;
    const bool pf = (i < 7);
    STG_A(T1, 1);
    RD_AF(0, 0); RD_BF(0, 0);
    BAR; LGKM0; MM16(0, 0); BAR;
    STG_B(T1, 0);
    RD_BF(0, 1);
    BAR; LGKM0; MM16(0, 1); BAR;
    STG_B(T1, 1);
    RD_AF(0, 1);
    BAR; LGKM0; MM16(1, 1); BAR;
    if (pf) STG_A(T2, 0);
    RD_BF(0, 0);
    BAR; LGKM0; MM16(1, 0);
    if (pf) asm volatile("s_waitcnt vmcnt(2)" ::: "memory");
    else    asm volatile("s_waitcnt vmcnt(0)" ::: "memory");
    BAR;
    if (pf) STG_A(T2, 1);
    RD_AF(1, 0); RD_BF(1, 0);
    BAR; LGKM0; MM16(0, 0); BAR;
    if (pf) STG_B(T2, 0);
    RD_BF(1, 1);
    BAR; LGKM0; MM16(0, 1); BAR;
    if (pf) STG_B(T2, 1);
    RD_AF(1, 1);
    BAR; LGKM0; MM16(1, 1); BAR;
    if (pf) STG_A(T3, 0);
    RD_BF(1, 0);
    BAR; LGKM0; MM16(1, 0);
    asm volatile("s_waitcnt vmcnt(2)" ::: "memory");
    BAR;
  }

  const float sc = (bcol < 1024) ? q_scale : 1.0f;
  const int crow0 = brow + wr * 128 + lg * 4;
  const int ccol0 = bcol + wc * 64 + l15;
#pragma unroll
  for (int m = 0; m < 8; ++m)
#pragma unroll
    for (int n = 0; n < 4; ++n)
#pragma unroll
      for (int r = 0; r < 4; ++r)
        C[(size_t)(crow0 + m * 16 + r) * 3072 + ccol0 + n * 16] =
            (bf16_t)(acc[m][n][r] * sc);
#undef STG_A
#undef STG_B
#undef RD_AF
#undef RD_BF
#undef MM16
}

// ------- GEMM2: 128x256-tile, 4-phase, triple-buffered (grid 256) ------
template <typename OutT>
__global__ __launch_bounds__(512, 1) void gemm_bt_128x256(
    const bf16_t* __restrict__ A, const bf16_t* __restrict__ Bt,
    OutT* __restrict__ C, int N, int nrowblk, int q_cols, float q_scale) {
  constexpr int K = 1024;
  extern __shared__ char smem[];
  char* asB = smem;            // 3 x 16 KB : A [buf][128][64]
  char* bsB = smem + 49152;    // 3 x 32 KB : B [buf][2half][128][64]

  const int t = threadIdx.x;
  const int lane = t & 63, wave = t >> 6;
  const int l15 = lane & 15, lg = lane >> 4;
  const int wr = wave >> 2, wc = wave & 3;

  const int cpx = (int)gridDim.x >> 3;
  const int bid = blockIdx.x;
  const int wg = (bid & 7) * cpx + (bid >> 3);
  const int brow = (wg % nrowblk) * 128;
  const int bcol = (wg / nrowblk) * 256;

  const int srow = t >> 3;
  const int schk = (t & 7) ^ (srow & 7);
  const bf16_t* aS = A + (size_t)(brow + srow) * K + schk * 8;
  const bf16_t* bS = Bt + (size_t)(bcol + srow) * K + schk * 8;
  const int ldst = t * 8;

#define STG_A(T, BUF) do {                                               \
    const bf16_t* _s = aS + (T) * 64;                                    \
    bf16_t* _d = (bf16_t*)(asB + (BUF) * 16384) + ldst;                  \
    GLOAD_LDS16(_s, _d);                                                 \
    GLOAD_LDS16(_s + (size_t)64 * K, _d + 4096);                         \
  } while (0)
#define STG_B(T, H, BUF) do {                                            \
    const bf16_t* _s = bS + (size_t)((H) * 128) * K + (T) * 64;          \
    bf16_t* _d = (bf16_t*)(bsB + (BUF) * 32768 + (H) * 16384) + ldst;    \
    GLOAD_LDS16(_s, _d);                                                 \
    GLOAD_LDS16(_s + (size_t)64 * K, _d + 4096);                         \
  } while (0)

  const int rx = l15 & 7;
  const unsigned c0 = ((unsigned)(lg ^ rx)) << 4;
  const unsigned c1 = ((unsigned)((4 | lg) ^ rx)) << 4;
  const unsigned a_rd = (unsigned)(wr * 8192 + l15 * 128);
  const unsigned b_rd = (unsigned)((wc >> 1) * 16384 + (wc & 1) * 8192 + l15 * 128);

  f32x4 acc[4][4] = {};
  bf16x8 af[2][2], bfr[4][2];

#define RD_AF(BUF, MH) do { _Pragma("unroll")                            \
    for (int m = 0; m < 2; ++m) {                                        \
      const char* _p = asB + (BUF) * 16384 + a_rd + ((MH) * 2 + m) * 2048; \
      af[m][0] = *(const bf16x8*)(_p + c0);                              \
      af[m][1] = *(const bf16x8*)(_p + c1); } } while (0)
#define RD_BF(BUF) do { _Pragma("unroll")                                \
    for (int n = 0; n < 4; ++n) {                                        \
      const char* _p = bsB + (BUF) * 32768 + b_rd + n * 2048;            \
      bfr[n][0] = *(const bf16x8*)(_p + c0);                             \
      bfr[n][1] = *(const bf16x8*)(_p + c1); } } while (0)
#define MM(MH) do {                                                      \
    __builtin_amdgcn_s_setprio(1);                                       \
    _Pragma("unroll")                                                    \
    for (int m = 0; m < 2; ++m) { _Pragma("unroll")                      \
      for (int n = 0; n < 4; ++n) {                                      \
        acc[(MH)*2+m][n] =                                               \
            MFMA_16x16x32(af[m][0], bfr[n][0], acc[(MH)*2+m][n]);        \
        acc[(MH)*2+m][n] =                                               \
            MFMA_16x16x32(af[m][1], bfr[n][1], acc[(MH)*2+m][n]); } }    \
    __builtin_amdgcn_s_setprio(0); } while (0)

  STG_A(0, 0); STG_B(0, 0, 0); STG_B(0, 1, 0);
  STG_A(1, 1); STG_B(1, 0, 1); STG_B(1, 1, 1);
  asm volatile("s_waitcnt vmcnt(6)" ::: "memory");
  BAR;

  int bc = 0;
  for (int T = 0; T < 16; ++T) {
    const bool pf = (T + 2 < 16);
    const int bs = (bc >= 1) ? (bc - 1) : 2;
    if (pf) { STG_A(T + 2, bs); STG_B(T + 2, 0, bs); }
    RD_AF(bc, 0);
    RD_BF(bc);
    BAR; LGKM0; MM(0); BAR;
    if (pf) STG_B(T + 2, 1, bs);
    RD_AF(bc, 1);
    BAR; LGKM0; MM(1);
    if (pf) asm volatile("s_waitcnt vmcnt(6)" ::: "memory");
    else    asm volatile("s_waitcnt vmcnt(0)" ::: "memory");
    BAR;
    bc = (bc == 2) ? 0 : bc + 1;
  }

  const float sc = (bcol < q_cols) ? q_scale : 1.0f;
  const int crow0 = brow + wr * 64 + lg * 4;
  const int ccol0 = bcol + wc * 64 + l15;
#pragma unroll
  for (int m = 0; m < 4; ++m)
#pragma unroll
    for (int n = 0; n < 4; ++n)
#pragma unroll
      for (int r = 0; r < 4; ++r)
        C[(size_t)(crow0 + m * 16 + r) * N + ccol0 + n * 16] =
            (OutT)(acc[m][n][r] * sc);
#undef STG_A
#undef STG_B
#undef RD_AF
#undef RD_BF
#undef MM
}

// ---- fused attention (v14: 256 q-rows/block, grid 512 = 2 blocks/CU) ----
// K/V staged once per tile serve 256 q-rows (2x amortization); grid 512 all
// resident in one round (no 1.33-round tail). Per iter: QK(s2=0) -> issue 16
// tr-reads -> softmax(0)+dn(0) -> QK(s2=1) -> softmax(1)+dn(1) -> lgkm(0) ->
// PV(both, 16x16x16 direct-feed) -> syncthreads.
__device__ __forceinline__ unsigned pack_bf16_pair(float a, float b) {
  union { __hip_bfloat162 h; unsigned u; } c;
  c.h = __float22bfloat162_rn(float2{a, b});  // v_cvt_pk_bf16_f32
  return c.u;
}

__global__ __launch_bounds__(256, 2) void attn_kernel(const bf16_t* __restrict__ qkv,
                                                      bf16_t* __restrict__ ctx) {
  __shared__ bf16_t Ks[2][4096];  // swizzled K, double-buffered (16 KB)
  __shared__ bf16_t Vs[2][4096];  // pi-subtiled V, double-buffered (16 KB)
  const int tid = threadIdx.x, lane = tid & 63, wave = tid >> 6;
  const int l15 = lane & 15, lg = (lane >> 4) & 3;
  // 512 blocks: all 4 supertiles of one (h,b) on one XCD
  const int flat = blockIdx.x;
  const int xcd = flat & 7, rr = flat >> 3;     // rr 0..63
  const int qt2 = rr & 3;                       // 256-row supertile
  const int hb = xcd * 16 + (rr >> 2);          // 0..127
  const int h = hb & 15, b = hb >> 4;
  const size_t base = (size_t)b * 1024 * LD;
  const int qbase = qt2 * 256 + wave * 32;      // s2 adds 128

  bf16x8 qa[2][2][2];  // [s2][s][half]
#pragma unroll
  for (int s2 = 0; s2 < 2; s2++)
#pragma unroll
    for (int s = 0; s < 2; s++) {
      const bf16_t* qp =
          qkv + base + (size_t)(qbase + s2 * 128 + s * 16 + l15) * LD + h * 64 + lg * 8;
      qa[s2][s][0] = *reinterpret_cast<const bf16x8*>(qp);
      qa[s2][s][1] = *reinterpret_cast<const bf16x8*>(qp + 32);
    }

  const bf16_t* Kb = qkv + base + 1024 + h * 64;
  const bf16_t* Vb = qkv + base + 2048 + h * 64;

  const int krr = lane >> 3;
  const int kcc = (lane & 7) ^ krr;
  const bf16_t* ksrc0 = Kb + (size_t)(wave * 16 + krr) * LD + kcc * 8;
  const bf16_t* ksrc1 = ksrc0 + (size_t)8 * LD;

  const int vd0 = (lane & 1) * 8 + wave * 16;
  const int vkv = ((lane >> 1) & 3) + ((lane >> 3) & 3) * 4 + (lane >> 5) * 16;
  const bf16_t* vsrc0 = Vb + (size_t)vkv * LD + vd0;
  const bf16_t* vsrc1 = vsrc0 + (size_t)32 * LD;

  bf16_t* ksb = &Ks[0][0];
  bf16_t* vsb = &Vs[0][0];
  const char* ksr = (const char*)&Ks[0][0];
  const unsigned vs_byte =
      (unsigned)(size_t)(__attribute__((address_space(3))) void*)(&Vs[0][0]);
  const unsigned tr_lane = vs_byte + lane * 8;

  const int rx7 = l15 & 7;
  const unsigned kb0 = (unsigned)(l15 * 128 + ((lg ^ rx7) << 4));
  const unsigned kb1 = (unsigned)(l15 * 128 + (((4 | lg) ^ rx7) << 4));

  short4v ones4;
#pragma unroll
  for (int j = 0; j < 4; j++) {
    union { bf16_t f; short s; } cu; cu.f = (bf16_t)1.0f;
    ones4[j] = cu.s;
  }

  f32x4 dn[2][2] = {};       // [s2][s]
  f32x4 oacc[2][2][4] = {};  // [s2][s][dt]

  GLOAD_LDS16(ksrc0, ksb + wave * 1024);
  GLOAD_LDS16(ksrc1, ksb + wave * 1024 + 512);
  GLOAD_LDS16(vsrc0, vsb + wave * 1024);
  GLOAD_LDS16(vsrc1, vsb + wave * 1024 + 512);
  ksrc0 += (size_t)64 * LD; ksrc1 += (size_t)64 * LD;
  vsrc0 += (size_t)64 * LD; vsrc1 += (size_t)64 * LD;
  __syncthreads();

#pragma unroll 2
  for (int t = 0; t < 16; t++) {
    const int cur = t & 1;
    if (t < 15) {
      bf16_t* kd = ksb + (cur ^ 1) * 4096 + wave * 1024;
      bf16_t* vd = vsb + (cur ^ 1) * 4096 + wave * 1024;
      GLOAD_LDS16(ksrc0, kd);
      GLOAD_LDS16(ksrc1, kd + 512);
      GLOAD_LDS16(vsrc0, vd);
      GLOAD_LDS16(vsrc1, vd + 512);
      ksrc0 += (size_t)64 * LD; ksrc1 += (size_t)64 * LD;
      vsrc0 += (size_t)64 * LD; vsrc1 += (size_t)64 * LD;
    }

    const char* kt = ksr + cur * 8192;
    const unsigned ta = tr_lane + (unsigned)cur * 8192;
    short4v paL[2][2][2], paH[2][2][2];  // [s2][s][ks]

    // ---- QK s2=0 ----
    f32x4 sacc0[2][4] = {};
    __builtin_amdgcn_s_setprio(1);
#pragma unroll
    for (int tt = 0; tt < 4; tt++) {
      const bf16x8 k0 = *reinterpret_cast<const bf16x8*>(kt + tt * 2048 + kb0);
      const bf16x8 k1 = *reinterpret_cast<const bf16x8*>(kt + tt * 2048 + kb1);
      sacc0[0][tt] = MFMA_16x16x32(k0, qa[0][0][0], sacc0[0][tt]);
      sacc0[0][tt] = MFMA_16x16x32(k1, qa[0][0][1], sacc0[0][tt]);
      sacc0[1][tt] = MFMA_16x16x32(k0, qa[0][1][0], sacc0[1][tt]);
      sacc0[1][tt] = MFMA_16x16x32(k1, qa[0][1][1], sacc0[1][tt]);
    }
    __builtin_amdgcn_s_setprio(0);

    // ---- issue all 16 tr-reads; latency hides under sm0 + QK1 + sm1 ----
    short4v tl0, th0, tl1, th1, tl2, th2, tl3, th3;
    short4v tl4, th4, tl5, th5, tl6, th6, tl7, th7;
    TRREAD(tl0, ta, "0");    TRREAD(th0, ta, "512");
    TRREAD(tl1, ta, "1024"); TRREAD(th1, ta, "1536");
    TRREAD(tl2, ta, "2048"); TRREAD(th2, ta, "2560");
    TRREAD(tl3, ta, "3072"); TRREAD(th3, ta, "3584");
    TRREAD(tl4, ta, "4096"); TRREAD(th4, ta, "4608");
    TRREAD(tl5, ta, "5120"); TRREAD(th5, ta, "5632");
    TRREAD(tl6, ta, "6144"); TRREAD(th6, ta, "6656");
    TRREAD(tl7, ta, "7168"); TRREAD(th7, ta, "7680");
    __builtin_amdgcn_sched_barrier(0);

    // ---- softmax s2=0 ----
    {
      unsigned pu[16];
#pragma unroll
      for (int tt = 0; tt < 4; tt++) {
#pragma unroll
        for (int s = 0; s < 2; s++) {
          const float p0 = __builtin_exp2f(sacc0[s][tt][0]);
          const float p1 = __builtin_exp2f(sacc0[s][tt][1]);
          const float p2 = __builtin_exp2f(sacc0[s][tt][2]);
          const float p3 = __builtin_exp2f(sacc0[s][tt][3]);
          pu[s * 8 + (tt >> 1) * 4 + (tt & 1) * 2 + 0] = pack_bf16_pair(p0, p1);
          pu[s * 8 + (tt >> 1) * 4 + (tt & 1) * 2 + 1] = pack_bf16_pair(p2, p3);
        }
      }
#pragma unroll
      for (int s = 0; s < 2; s++)
#pragma unroll
        for (int ks = 0; ks < 2; ks++) {
          paL[0][s][ks] = *reinterpret_cast<short4v*>(&pu[s * 8 + ks * 4]);
          paH[0][s][ks] = *reinterpret_cast<short4v*>(&pu[s * 8 + ks * 4 + 2]);
          dn[0][s] = MFMA16(paL[0][s][ks], ones4, dn[0][s]);
          dn[0][s] = MFMA16(paH[0][s][ks], ones4, dn[0][s]);
        }
    }

    // ---- QK s2=1 (K frags re-read from LDS) ----
    f32x4 sacc1[2][4] = {};
    __builtin_amdgcn_s_setprio(1);
#pragma unroll
    for (int tt = 0; tt < 4; tt++) {
      const bf16x8 k0 = *reinterpret_cast<const bf16x8*>(kt + tt * 2048 + kb0);
      const bf16x8 k1 = *reinterpret_cast<const bf16x8*>(kt + tt * 2048 + kb1);
      sacc1[0][tt] = MFMA_16x16x32(k0, qa[1][0][0], sacc1[0][tt]);
      sacc1[0][tt] = MFMA_16x16x32(k1, qa[1][0][1], sacc1[0][tt]);
      sacc1[1][tt] = MFMA_16x16x32(k0, qa[1][1][0], sacc1[1][tt]);
      sacc1[1][tt] = MFMA_16x16x32(k1, qa[1][1][1], sacc1[1][tt]);
    }
    __builtin_amdgcn_s_setprio(0);

    // ---- softmax s2=1 ----
    {
      unsigned pu[16];
#pragma unroll
      for (int tt = 0; tt < 4; tt++) {
#pragma unroll
        for (int s = 0; s < 2; s++) {
          const float p0 = __builtin_exp2f(sacc1[s][tt][0]);
          const float p1 = __builtin_exp2f(sacc1[s][tt][1]);
          const float p2 = __builtin_exp2f(sacc1[s][tt][2]);
          const float p3 = __builtin_exp2f(sacc1[s][tt][3]);
          pu[s * 8 + (tt >> 1) * 4 + (tt & 1) * 2 + 0] = pack_bf16_pair(p0, p1);
          pu[s * 8 + (tt >> 1) * 4 + (tt & 1) * 2 + 1] = pack_bf16_pair(p2, p3);
        }
      }
#pragma unroll
      for (int s = 0; s < 2; s++)
#pragma unroll
        for (int ks = 0; ks < 2; ks++) {
          paL[1][s][ks] = *reinterpret_cast<short4v*>(&pu[s * 8 + ks * 4]);
          paH[1][s][ks] = *reinterpret_cast<short4v*>(&pu[s * 8 + ks * 4 + 2]);
          dn[1][s] = MFMA16(paL[1][s][ks], ones4, dn[1][s]);
          dn[1][s] = MFMA16(paH[1][s][ks], ones4, dn[1][s]);
        }
    }

    LGKM0;  // all tr-reads + K reads complete

    // ---- PV both s2 (16x16x16 direct-feed; tr regs pair with pa quarters) ----
    __builtin_amdgcn_s_setprio(1);
#pragma unroll
    for (int s2 = 0; s2 < 2; s2++)
#pragma unroll
      for (int s = 0; s < 2; s++) {
        oacc[s2][s][0] = MFMA16(paL[s2][s][0], tl0, oacc[s2][s][0]);
        oacc[s2][s][0] = MFMA16(paH[s2][s][0], th0, oacc[s2][s][0]);
        oacc[s2][s][0] = MFMA16(paL[s2][s][1], tl1, oacc[s2][s][0]);
        oacc[s2][s][0] = MFMA16(paH[s2][s][1], th1, oacc[s2][s][0]);
        oacc[s2][s][1] = MFMA16(paL[s2][s][0], tl2, oacc[s2][s][1]);
        oacc[s2][s][1] = MFMA16(paH[s2][s][0], th2, oacc[s2][s][1]);
        oacc[s2][s][1] = MFMA16(paL[s2][s][1], tl3, oacc[s2][s][1]);
        oacc[s2][s][1] = MFMA16(paH[s2][s][1], th3, oacc[s2][s][1]);
        oacc[s2][s][2] = MFMA16(paL[s2][s][0], tl4, oacc[s2][s][2]);
        oacc[s2][s][2] = MFMA16(paH[s2][s][0], th4, oacc[s2][s][2]);
        oacc[s2][s][2] = MFMA16(paL[s2][s][1], tl5, oacc[s2][s][2]);
        oacc[s2][s][2] = MFMA16(paH[s2][s][1], th5, oacc[s2][s][2]);
        oacc[s2][s][3] = MFMA16(paL[s2][s][0], tl6, oacc[s2][s][3]);
        oacc[s2][s][3] = MFMA16(paH[s2][s][0], th6, oacc[s2][s][3]);
        oacc[s2][s][3] = MFMA16(paL[s2][s][1], tl7, oacc[s2][s][3]);
        oacc[s2][s][3] = MFMA16(paH[s2][s][1], th7, oacc[s2][s][3]);
      }
    __builtin_amdgcn_s_setprio(0);

    __syncthreads();
  }

  // ---- epilogue: per-lane denominators ----
#pragma unroll
  for (int s2 = 0; s2 < 2; s2++)
#pragma unroll
    for (int s = 0; s < 2; s++)
#pragma unroll
      for (int r = 0; r < 4; r++) {
        const float inv = 1.0f / dn[s2][s][r];
        const size_t row =
            (size_t)(b * 1024 + qbase + s2 * 128 + s * 16 + lg * 4 + r);
#pragma unroll
        for (int dt = 0; dt < 4; dt++)
          ctx[row * 1024 + h * 64 + dt * 16 + l15] =
              (bf16_t)(oacc[s2][s][dt][r] * inv);
      }
}

extern "C" void kernel_launch(void* const* d_in, const int* in_sizes, int n_in,
                              void* d_out, int out_size, void* d_ws, size_t ws_size,
                              hipStream_t stream) {
  (void)in_sizes; (void)n_in; (void)out_size; (void)ws_size;
  const float* x = (const float*)d_in[0];
  const float* w_qkv = (const float*)d_in[1];
  const float* w_out = (const float*)d_in[2];
  float* out = (float*)d_out;
  char* ws = (char*)d_ws;

  bf16_t* x_b   = (bf16_t*)(ws);                        // 16 MB
  bf16_t* qkv_b = (bf16_t*)(ws + (size_t)(16 << 20));   // 48 MB
  bf16_t* wqT   = (bf16_t*)(ws + (size_t)(64 << 20));   // 6 MB
  bf16_t* woT   = (bf16_t*)(ws + (size_t)(70 << 20));   // 2 MB
  bf16_t* ctx_b = (bf16_t*)(ws + (size_t)(72 << 20));   // 16 MB

  const float qsc = 0.045084220027780106f;  // log2(e)/32

  prep_kernel<<<8192, 256, 0, stream>>>(x, x_b, w_qkv, wqT, w_out, woT);
  gemm_qkv_256<<<384, 512, 131072, stream>>>(x_b, wqT, qkv_b, qsc);
  attn_kernel<<<512, 256, 0, stream>>>(qkv_b, ctx_b);
  gemm_bt_128x256<float><<<256, 512, 147456, stream>>>(
      ctx_b, woT, out, 1024, 64, 0, 1.0f);
}

// Round 19
// 151.989 us; speedup vs baseline: 1.0377x; 1.0377x over previous
//
#include <hip/hip_runtime.h>
#include <hip/hip_bf16.h>

typedef __bf16 bf16_t;
typedef __bf16 bf16x8 __attribute__((ext_vector_type(8)));
typedef __bf16 bf16x4 __attribute__((ext_vector_type(4)));
typedef float f32x4 __attribute__((ext_vector_type(4)));

constexpr int LD = 3072;

#define MFMA_16x16x32(a, b, c) __builtin_amdgcn_mfma_f32_16x16x32_bf16((a), (b), (c), 0, 0, 0)

#define GLOAD_LDS16(g, l)                                               \
  __builtin_amdgcn_global_load_lds(                                     \
      (const __attribute__((address_space(1))) void*)(g),               \
      (__attribute__((address_space(3))) void*)(l), 16, 0, 0)

#define TRREAD(dst, addr, imm) \
  asm volatile("ds_read_b64_tr_b16 %0, %1 offset:" imm : "=v"(dst) : "v"(addr))

#define BAR __builtin_amdgcn_s_barrier()
#define LGKM0 do { asm volatile("s_waitcnt lgkmcnt(0)" ::: "memory"); \
                   __builtin_amdgcn_sched_barrier(0); } while (0)

// ---- fused prep: cvt(x) + tcvt(w_qkv) + tcvt(w_out) in one launch ----
__global__ __launch_bounds__(256) void prep_kernel(
    const float* __restrict__ x, bf16_t* __restrict__ x_b,
    const float* __restrict__ w_qkv, bf16_t* __restrict__ wqT,
    const float* __restrict__ w_out, bf16_t* __restrict__ woT) {
  const int blk = blockIdx.x;
  if (blk < 4096) {
    const int i = blk * 256 + threadIdx.x;
    const float4 a = reinterpret_cast<const float4*>(x)[2 * i];
    const float4 c = reinterpret_cast<const float4*>(x)[2 * i + 1];
    bf16x8 o;
    o[0] = (bf16_t)a.x; o[1] = (bf16_t)a.y; o[2] = (bf16_t)a.z; o[3] = (bf16_t)a.w;
    o[4] = (bf16_t)c.x; o[5] = (bf16_t)c.y; o[6] = (bf16_t)c.z; o[7] = (bf16_t)c.w;
    reinterpret_cast<bf16x8*>(x_b)[i] = o;
    return;
  }
  __shared__ float tile[32][33];
  const float* in; bf16_t* outp; int C, bx, by;
  if (blk < 7168) { const int i = blk - 4096; in = w_qkv; outp = wqT; C = 3072; bx = i % 96; by = i / 96; }
  else            { const int i = blk - 7168; in = w_out; outp = woT; C = 1024; bx = i & 31; by = i >> 5; }
  constexpr int R = 1024;
  const int c0 = bx * 32, r0 = by * 32;
  const int tx = threadIdx.x & 31, ty = threadIdx.x >> 5;
#pragma unroll
  for (int i = 0; i < 32; i += 8)
    tile[ty + i][tx] = in[(size_t)(r0 + ty + i) * C + (c0 + tx)];
  __syncthreads();
#pragma unroll
  for (int i = 0; i < 32; i += 8)
    outp[(size_t)(c0 + ty + i) * R + (r0 + tx)] = (bf16_t)tile[tx][ty + i];
}

// ------------- GEMM1 (QKV): 256x256 tile, 8-phase, counted vmcnt -------------
// 2-D XCD chunking: each XCD owns an 8-row x 6-col rectangle of the 32x12 grid.
__global__ __launch_bounds__(512, 2) void gemm_qkv_256(
    const bf16_t* __restrict__ A, const bf16_t* __restrict__ Bt,
    bf16_t* __restrict__ C, float q_scale) {
  constexpr int K = 1024;
  extern __shared__ char smem[];
  char* asB = smem;           // 64 KB: A [2][2][128][64]
  char* bsB = smem + 65536;   // 64 KB: B

  const int t = threadIdx.x;
  const int lane = t & 63, wave = t >> 6;
  const int l15 = lane & 15, lg = lane >> 4;
  const int wr = wave >> 2, wc = wave & 3;

  const int bid = blockIdx.x;
  const int idx = bid >> 3;
  const int rgrp = (bid >> 1) & 3;
  const int cgrp = bid & 1;
  const int brow = (rgrp * 8 + (idx & 7)) * 256;
  const int bcol = (cgrp * 6 + (idx >> 3)) * 256;

  const int srow = t >> 3;
  const int schk = (t & 7) ^ (srow & 7);
  const bf16_t* aS = A + (size_t)(brow + srow) * K + schk * 8;
  const bf16_t* bS = Bt + (size_t)(bcol + srow) * K + schk * 8;
  const int ldst = t * 8;

#define STG_A(T, H) do {                                                      \
    const bf16_t* _s = aS + (size_t)((H) * 128) * K + (T) * 64;               \
    bf16_t* _d = (bf16_t*)(asB + ((T) & 1) * 32768 + (H) * 16384) + ldst;     \
    GLOAD_LDS16(_s, _d);                                                      \
    GLOAD_LDS16(_s + (size_t)64 * K, _d + 4096);                              \
  } while (0)
#define STG_B(T, H) do {                                                      \
    const bf16_t* _s = bS + (size_t)((H) * 128) * K + (T) * 64;               \
    bf16_t* _d = (bf16_t*)(bsB + ((T) & 1) * 32768 + (H) * 16384) + ldst;     \
    GLOAD_LDS16(_s, _d);                                                      \
    GLOAD_LDS16(_s + (size_t)64 * K, _d + 4096);                              \
  } while (0)

  const int rx = l15 & 7;
  const unsigned c0 = ((unsigned)(lg ^ rx)) << 4;
  const unsigned c1 = ((unsigned)((4 | lg) ^ rx)) << 4;
  const unsigned a_rd = (unsigned)(wr * 16384 + l15 * 128);
  const unsigned b_rd = (unsigned)((wc >> 1) * 16384 + (wc & 1) * 8192 + l15 * 128);

  f32x4 acc[8][4] = {};
  bf16x8 af[4][2], bfr[2][2];

#define RD_AF(BUF, MH) do { _Pragma("unroll")                                 \
    for (int m = 0; m < 4; ++m) {                                             \
      const char* _p = asB + (BUF) * 32768 + a_rd + ((MH) * 4 + m) * 2048;    \
      af[m][0] = *(const bf16x8*)(_p + c0);                                   \
      af[m][1] = *(const bf16x8*)(_p + c1); } } while (0)
#define RD_BF(BUF, NH) do { _Pragma("unroll")                                 \
    for (int n = 0; n < 2; ++n) {                                             \
      const char* _p = bsB + (BUF) * 32768 + b_rd + ((NH) * 2 + n) * 2048;    \
      bfr[n][0] = *(const bf16x8*)(_p + c0);                                  \
      bfr[n][1] = *(const bf16x8*)(_p + c1); } } while (0)
#define MM16(MH, NH) do {                                                     \
    __builtin_amdgcn_s_setprio(1);                                            \
    _Pragma("unroll")                                                         \
    for (int m = 0; m < 4; ++m) { _Pragma("unroll")                           \
      for (int n = 0; n < 2; ++n) {                                           \
        acc[(MH)*4+m][(NH)*2+n] =                                             \
            MFMA_16x16x32(af[m][0], bfr[n][0], acc[(MH)*4+m][(NH)*2+n]);      \
        acc[(MH)*4+m][(NH)*2+n] =                                             \
            MFMA_16x16x32(af[m][1], bfr[n][1], acc[(MH)*4+m][(NH)*2+n]); } }  \
    __builtin_amdgcn_s_setprio(0); } while (0)

  STG_A(0, 0); STG_A(0, 1); STG_B(0, 0); STG_B(0, 1); STG_A(1, 0);
  asm volatile("s_waitcnt vmcnt(2)" ::: "memory");
  BAR;

  for (int i = 0; i < 8; ++i) {
    const int T1 = 2 * i + 1, T2 = 2 * i + 2, T3 = 2 * i + 3;
    const bool pf = (i < 7);
    STG_A(T1, 1);
    RD_AF(0, 0); RD_BF(0, 0);
    BAR; LGKM0; MM16(0, 0); BAR;
    STG_B(T1, 0);
    RD_BF(0, 1);
    BAR; LGKM0; MM16(0, 1); BAR;
    STG_B(T1, 1);
    RD_AF(0, 1);
    BAR; LGKM0; MM16(1, 1); BAR;
    if (pf) STG_A(T2, 0);
    RD_BF(0, 0);
    BAR; LGKM0; MM16(1, 0);
    if (pf) asm volatile("s_waitcnt vmcnt(2)" ::: "memory");
    else    asm volatile("s_waitcnt vmcnt(0)" ::: "memory");
    BAR;
    if (pf) STG_A(T2, 1);
    RD_AF(1, 0); RD_BF(1, 0);
    BAR; LGKM0; MM16(0, 0); BAR;
    if (pf) STG_B(T2, 0);
    RD_BF(1, 1);
    BAR; LGKM0; MM16(0, 1); BAR;
    if (pf) STG_B(T2, 1);
    RD_AF(1, 1);
    BAR; LGKM0; MM16(1, 1); BAR;
    if (pf) STG_A(T3, 0);
    RD_BF(1, 0);
    BAR; LGKM0; MM16(1, 0);
    asm volatile("s_waitcnt vmcnt(2)" ::: "memory");
    BAR;
  }

  const float sc = (bcol < 1024) ? q_scale : 1.0f;
  const int crow0 = brow + wr * 128 + lg * 4;
  const int ccol0 = bcol + wc * 64 + l15;
#pragma unroll
  for (int m = 0; m < 8; ++m)
#pragma unroll
    for (int n = 0; n < 4; ++n)
#pragma unroll
      for (int r = 0; r < 4; ++r)
        C[(size_t)(crow0 + m * 16 + r) * 3072 + ccol0 + n * 16] =
            (bf16_t)(acc[m][n][r] * sc);
#undef STG_A
#undef STG_B
#undef RD_AF
#undef RD_BF
#undef MM16
}

// ------- GEMM2: 128x256-tile, 4-phase, triple-buffered (grid 256) ------
template <typename OutT>
__global__ __launch_bounds__(512, 1) void gemm_bt_128x256(
    const bf16_t* __restrict__ A, const bf16_t* __restrict__ Bt,
    OutT* __restrict__ C, int N, int nrowblk, int q_cols, float q_scale) {
  constexpr int K = 1024;
  extern __shared__ char smem[];
  char* asB = smem;            // 3 x 16 KB : A [buf][128][64]
  char* bsB = smem + 49152;    // 3 x 32 KB : B [buf][2half][128][64]

  const int t = threadIdx.x;
  const int lane = t & 63, wave = t >> 6;
  const int l15 = lane & 15, lg = lane >> 4;
  const int wr = wave >> 2, wc = wave & 3;

  const int cpx = (int)gridDim.x >> 3;
  const int bid = blockIdx.x;
  const int wg = (bid & 7) * cpx + (bid >> 3);
  const int brow = (wg % nrowblk) * 128;
  const int bcol = (wg / nrowblk) * 256;

  const int srow = t >> 3;
  const int schk = (t & 7) ^ (srow & 7);
  const bf16_t* aS = A + (size_t)(brow + srow) * K + schk * 8;
  const bf16_t* bS = Bt + (size_t)(bcol + srow) * K + schk * 8;
  const int ldst = t * 8;

#define STG_A(T, BUF) do {                                               \
    const bf16_t* _s = aS + (T) * 64;                                    \
    bf16_t* _d = (bf16_t*)(asB + (BUF) * 16384) + ldst;                  \
    GLOAD_LDS16(_s, _d);                                                 \
    GLOAD_LDS16(_s + (size_t)64 * K, _d + 4096);                         \
  } while (0)
#define STG_B(T, H, BUF) do {                                            \
    const bf16_t* _s = bS + (size_t)((H) * 128) * K + (T) * 64;          \
    bf16_t* _d = (bf16_t*)(bsB + (BUF) * 32768 + (H) * 16384) + ldst;    \
    GLOAD_LDS16(_s, _d);                                                 \
    GLOAD_LDS16(_s + (size_t)64 * K, _d + 4096);                         \
  } while (0)

  const int rx = l15 & 7;
  const unsigned c0 = ((unsigned)(lg ^ rx)) << 4;
  const unsigned c1 = ((unsigned)((4 | lg) ^ rx)) << 4;
  const unsigned a_rd = (unsigned)(wr * 8192 + l15 * 128);
  const unsigned b_rd = (unsigned)((wc >> 1) * 16384 + (wc & 1) * 8192 + l15 * 128);

  f32x4 acc[4][4] = {};
  bf16x8 af[2][2], bfr[4][2];

#define RD_AF(BUF, MH) do { _Pragma("unroll")                            \
    for (int m = 0; m < 2; ++m) {                                        \
      const char* _p = asB + (BUF) * 16384 + a_rd + ((MH) * 2 + m) * 2048; \
      af[m][0] = *(const bf16x8*)(_p + c0);                              \
      af[m][1] = *(const bf16x8*)(_p + c1); } } while (0)
#define RD_BF(BUF) do { _Pragma("unroll")                                \
    for (int n = 0; n < 4; ++n) {                                        \
      const char* _p = bsB + (BUF) * 32768 + b_rd + n * 2048;            \
      bfr[n][0] = *(const bf16x8*)(_p + c0);                             \
      bfr[n][1] = *(const bf16x8*)(_p + c1); } } while (0)
#define MM(MH) do {                                                      \
    __builtin_amdgcn_s_setprio(1);                                       \
    _Pragma("unroll")                                                    \
    for (int m = 0; m < 2; ++m) { _Pragma("unroll")                      \
      for (int n = 0; n < 4; ++n) {                                      \
        acc[(MH)*2+m][n] =                                               \
            MFMA_16x16x32(af[m][0], bfr[n][0], acc[(MH)*2+m][n]);        \
        acc[(MH)*2+m][n] =                                               \
            MFMA_16x16x32(af[m][1], bfr[n][1], acc[(MH)*2+m][n]); } }    \
    __builtin_amdgcn_s_setprio(0); } while (0)

  STG_A(0, 0); STG_B(0, 0, 0); STG_B(0, 1, 0);
  STG_A(1, 1); STG_B(1, 0, 1); STG_B(1, 1, 1);
  asm volatile("s_waitcnt vmcnt(6)" ::: "memory");
  BAR;

  int bc = 0;
  for (int T = 0; T < 16; ++T) {
    const bool pf = (T + 2 < 16);
    const int bs = (bc >= 1) ? (bc - 1) : 2;
    if (pf) { STG_A(T + 2, bs); STG_B(T + 2, 0, bs); }
    RD_AF(bc, 0);
    RD_BF(bc);
    BAR; LGKM0; MM(0); BAR;
    if (pf) STG_B(T + 2, 1, bs);
    RD_AF(bc, 1);
    BAR; LGKM0; MM(1);
    if (pf) asm volatile("s_waitcnt vmcnt(6)" ::: "memory");
    else    asm volatile("s_waitcnt vmcnt(0)" ::: "memory");
    BAR;
    bc = (bc == 2) ? 0 : bc + 1;
  }

  const float sc = (bcol < q_cols) ? q_scale : 1.0f;
  const int crow0 = brow + wr * 64 + lg * 4;
  const int ccol0 = bcol + wc * 64 + l15;
#pragma unroll
  for (int m = 0; m < 4; ++m)
#pragma unroll
    for (int n = 0; n < 4; ++n)
#pragma unroll
      for (int r = 0; r < 4; ++r)
        C[(size_t)(crow0 + m * 16 + r) * N + ccol0 + n * 16] =
            (OutT)(acc[m][n][r] * sc);
#undef STG_A
#undef STG_B
#undef RD_AF
#undef RD_BF
#undef MM
}

// ------- fused attention (v12: double-buffer + unroll 4 + ones-MFMA dn) ------
__device__ __forceinline__ unsigned pack_bf16_pair(float a, float b) {
  union { __hip_bfloat162 h; unsigned u; } c;
  c.h = __float22bfloat162_rn(float2{a, b});  // v_cvt_pk_bf16_f32
  return c.u;
}

__global__ __launch_bounds__(256, 3) void attn_kernel(const bf16_t* __restrict__ qkv,
                                                      bf16_t* __restrict__ ctx) {
  __shared__ bf16_t Ks[2][4096];  // swizzled K, double-buffered (16 KB)
  __shared__ bf16_t Vs[2][4096];  // pi-subtiled V, double-buffered (16 KB)
  const int tid = threadIdx.x, lane = tid & 63, wave = tid >> 6;
  const int l15 = lane & 15, lg = (lane >> 4) & 3;
  const int flat = blockIdx.x;
  const int xcd = flat & 7, rr = flat >> 3;
  const int qt = rr & 7;
  const int hb = xcd * 16 + (rr >> 3);
  const int h = hb & 15, b = hb >> 4;
  const size_t base = (size_t)b * 1024 * LD;
  const int qbase = qt * 128 + wave * 32;

  bf16x8 qa[2][2];
#pragma unroll
  for (int s = 0; s < 2; s++) {
    const bf16_t* qp = qkv + base + (size_t)(qbase + s * 16 + l15) * LD + h * 64 + lg * 8;
    qa[s][0] = *reinterpret_cast<const bf16x8*>(qp);
    qa[s][1] = *reinterpret_cast<const bf16x8*>(qp + 32);
  }

  const bf16_t* Kb = qkv + base + 1024 + h * 64;
  const bf16_t* Vb = qkv + base + 2048 + h * 64;

  const int krr = lane >> 3;
  const int kcc = (lane & 7) ^ krr;
  const bf16_t* ksrc0 = Kb + (size_t)(wave * 16 + krr) * LD + kcc * 8;
  const bf16_t* ksrc1 = ksrc0 + (size_t)8 * LD;

  const int vd0 = (lane & 1) * 8 + wave * 16;
  const int vkv = ((lane >> 1) & 3) + ((lane >> 3) & 3) * 4 + (lane >> 5) * 16;
  const bf16_t* vsrc0 = Vb + (size_t)vkv * LD + vd0;
  const bf16_t* vsrc1 = vsrc0 + (size_t)32 * LD;

  bf16_t* ksb = &Ks[0][0];
  bf16_t* vsb = &Vs[0][0];
  const char* ksr = (const char*)&Ks[0][0];
  const unsigned vs_byte =
      (unsigned)(size_t)(__attribute__((address_space(3))) void*)(&Vs[0][0]);
  const unsigned tr_lane = vs_byte + lane * 8;

  const int rx7 = l15 & 7;
  const unsigned kb0 = (unsigned)(l15 * 128 + ((lg ^ rx7) << 4));
  const unsigned kb1 = (unsigned)(l15 * 128 + (((4 | lg) ^ rx7) << 4));

  bf16x8 ones;
#pragma unroll
  for (int j = 0; j < 8; j++) ones[j] = (bf16_t)1.0f;

  f32x4 dn[2] = {};
  f32x4 oacc[2][4] = {};

  GLOAD_LDS16(ksrc0, ksb + wave * 1024);
  GLOAD_LDS16(ksrc1, ksb + wave * 1024 + 512);
  GLOAD_LDS16(vsrc0, vsb + wave * 1024);
  GLOAD_LDS16(vsrc1, vsb + wave * 1024 + 512);
  ksrc0 += (size_t)64 * LD; ksrc1 += (size_t)64 * LD;
  vsrc0 += (size_t)64 * LD; vsrc1 += (size_t)64 * LD;
  __syncthreads();

#pragma unroll 4
  for (int t = 0; t < 16; t++) {
    const int cur = t & 1;
    if (t < 15) {
      bf16_t* kd = ksb + (cur ^ 1) * 4096 + wave * 1024;
      bf16_t* vd = vsb + (cur ^ 1) * 4096 + wave * 1024;
      GLOAD_LDS16(ksrc0, kd);
      GLOAD_LDS16(ksrc1, kd + 512);
      GLOAD_LDS16(vsrc0, vd);
      GLOAD_LDS16(vsrc1, vd + 512);
      ksrc0 += (size_t)64 * LD; ksrc1 += (size_t)64 * LD;
      vsrc0 += (size_t)64 * LD; vsrc1 += (size_t)64 * LD;
    }

    f32x4 sacc[2][4] = {};
    const char* kt = ksr + cur * 8192;
    __builtin_amdgcn_s_setprio(1);
#pragma unroll
    for (int tt = 0; tt < 4; tt++) {
      const bf16x8 k0 = *reinterpret_cast<const bf16x8*>(kt + tt * 2048 + kb0);
      const bf16x8 k1 = *reinterpret_cast<const bf16x8*>(kt + tt * 2048 + kb1);
      sacc[0][tt] = MFMA_16x16x32(k0, qa[0][0], sacc[0][tt]);
      sacc[0][tt] = MFMA_16x16x32(k1, qa[0][1], sacc[0][tt]);
      sacc[1][tt] = MFMA_16x16x32(k0, qa[1][0], sacc[1][tt]);
      sacc[1][tt] = MFMA_16x16x32(k1, qa[1][1], sacc[1][tt]);
    }
    __builtin_amdgcn_s_setprio(0);

    const unsigned ta = tr_lane + (unsigned)cur * 8192;
    bf16x4 tl0, th0, tl2, th2, tl4, th4, tl6, th6;
    TRREAD(tl0, ta, "0");    TRREAD(th0, ta, "512");
    TRREAD(tl2, ta, "2048"); TRREAD(th2, ta, "2560");
    TRREAD(tl4, ta, "4096"); TRREAD(th4, ta, "4608");
    TRREAD(tl6, ta, "6144"); TRREAD(th6, ta, "6656");
    __builtin_amdgcn_sched_barrier(0);

    unsigned pu[16];
#pragma unroll
    for (int tt = 0; tt < 4; tt++) {
      const float a0 = __builtin_exp2f(sacc[0][tt][0]);
      const float a1 = __builtin_exp2f(sacc[0][tt][1]);
      const float a2 = __builtin_exp2f(sacc[0][tt][2]);
      const float a3 = __builtin_exp2f(sacc[0][tt][3]);
      pu[(tt >> 1) * 4 + (tt & 1) * 2 + 0] = pack_bf16_pair(a0, a1);
      pu[(tt >> 1) * 4 + (tt & 1) * 2 + 1] = pack_bf16_pair(a2, a3);
      const float b0 = __builtin_exp2f(sacc[1][tt][0]);
      const float b1 = __builtin_exp2f(sacc[1][tt][1]);
      const float b2 = __builtin_exp2f(sacc[1][tt][2]);
      const float b3 = __builtin_exp2f(sacc[1][tt][3]);
      pu[8 + (tt >> 1) * 4 + (tt & 1) * 2 + 0] = pack_bf16_pair(b0, b1);
      pu[8 + (tt >> 1) * 4 + (tt & 1) * 2 + 1] = pack_bf16_pair(b2, b3);
    }
    bf16x8 pa[2][2];
    pa[0][0] = *reinterpret_cast<bf16x8*>(&pu[0]);
    pa[0][1] = *reinterpret_cast<bf16x8*>(&pu[4]);
    pa[1][0] = *reinterpret_cast<bf16x8*>(&pu[8]);
    pa[1][1] = *reinterpret_cast<bf16x8*>(&pu[12]);

    // denominator rides the matrix pipe
    dn[0] = MFMA_16x16x32(pa[0][0], ones, dn[0]);
    dn[0] = MFMA_16x16x32(pa[0][1], ones, dn[0]);
    dn[1] = MFMA_16x16x32(pa[1][0], ones, dn[1]);
    dn[1] = MFMA_16x16x32(pa[1][1], ones, dn[1]);

    bf16x4 tl1, th1, tl3, th3, tl5, th5, tl7, th7;
    TRREAD(tl1, ta, "1024"); TRREAD(th1, ta, "1536");
    TRREAD(tl3, ta, "3072"); TRREAD(th3, ta, "3584");
    TRREAD(tl5, ta, "5120"); TRREAD(th5, ta, "5632");
    TRREAD(tl7, ta, "7168"); TRREAD(th7, ta, "7680");

    asm volatile("s_waitcnt lgkmcnt(8)" ::: "memory");
    __builtin_amdgcn_sched_barrier(0);
    {
      bf16x8 vb0[4];
      vb0[0] = __builtin_shufflevector(tl0, th0, 0, 1, 2, 3, 4, 5, 6, 7);
      vb0[1] = __builtin_shufflevector(tl2, th2, 0, 1, 2, 3, 4, 5, 6, 7);
      vb0[2] = __builtin_shufflevector(tl4, th4, 0, 1, 2, 3, 4, 5, 6, 7);
      vb0[3] = __builtin_shufflevector(tl6, th6, 0, 1, 2, 3, 4, 5, 6, 7);
      __builtin_amdgcn_s_setprio(1);
#pragma unroll
      for (int s = 0; s < 2; s++)
#pragma unroll
        for (int dt = 0; dt < 4; dt++)
          oacc[s][dt] = MFMA_16x16x32(pa[s][0], vb0[dt], oacc[s][dt]);
      __builtin_amdgcn_s_setprio(0);
    }

    asm volatile("s_waitcnt lgkmcnt(0)" ::: "memory");
    __builtin_amdgcn_sched_barrier(0);
    {
      bf16x8 vb1[4];
      vb1[0] = __builtin_shufflevector(tl1, th1, 0, 1, 2, 3, 4, 5, 6, 7);
      vb1[1] = __builtin_shufflevector(tl3, th3, 0, 1, 2, 3, 4, 5, 6, 7);
      vb1[2] = __builtin_shufflevector(tl5, th5, 0, 1, 2, 3, 4, 5, 6, 7);
      vb1[3] = __builtin_shufflevector(tl7, th7, 0, 1, 2, 3, 4, 5, 6, 7);
      __builtin_amdgcn_s_setprio(1);
#pragma unroll
      for (int s = 0; s < 2; s++)
#pragma unroll
        for (int dt = 0; dt < 4; dt++)
          oacc[s][dt] = MFMA_16x16x32(pa[s][1], vb1[dt], oacc[s][dt]);
      __builtin_amdgcn_s_setprio(0);
    }

    __syncthreads();
  }

  // ---- epilogue: per-lane denominators ----
#pragma unroll
  for (int s = 0; s < 2; s++) {
#pragma unroll
    for (int r = 0; r < 4; r++) {
      const float inv = 1.0f / dn[s][r];
      const size_t row = (size_t)(b * 1024 + qbase + s * 16 + lg * 4 + r);
#pragma unroll
      for (int dt = 0; dt < 4; dt++)
        ctx[row * 1024 + h * 64 + dt * 16 + l15] = (bf16_t)(oacc[s][dt][r] * inv);
    }
  }
}

extern "C" void kernel_launch(void* const* d_in, const int* in_sizes, int n_in,
                              void* d_out, int out_size, void* d_ws, size_t ws_size,
                              hipStream_t stream) {
  (void)in_sizes; (void)n_in; (void)out_size; (void)ws_size;
  const float* x = (const float*)d_in[0];
  const float* w_qkv = (const float*)d_in[1];
  const float* w_out = (const float*)d_in[2];
  float* out = (float*)d_out;
  char* ws = (char*)d_ws;

  bf16_t* x_b   = (bf16_t*)(ws);                        // 16 MB
  bf16_t* qkv_b = (bf16_t*)(ws + (size_t)(16 << 20));   // 48 MB
  bf16_t* wqT   = (bf16_t*)(ws + (size_t)(64 << 20));   // 6 MB
  bf16_t* woT   = (bf16_t*)(ws + (size_t)(70 << 20));   // 2 MB
  bf16_t* ctx_b = (bf16_t*)(ws + (size_t)(72 << 20));   // 16 MB

  const float qsc = 0.045084220027780106f;  // log2(e)/32

  prep_kernel<<<8192, 256, 0, stream>>>(x, x_b, w_qkv, wqT, w_out, woT);
  gemm_qkv_256<<<384, 512, 131072, stream>>>(x_b, wqT, qkv_b, qsc);
  attn_kernel<<<1024, 256, 0, stream>>>(qkv_b, ctx_b);
  gemm_bt_128x256<float><<<256, 512, 147456, stream>>>(
      ctx_b, woT, out, 1024, 64, 0, 1.0f);
}